// Round 4
// baseline (229.026 us; speedup 1.0000x reference)
//
#include <hip/hip_runtime.h>
#include <hip/hip_bf16.h>

// ---------- types ----------
typedef __attribute__((ext_vector_type(8))) short bfx8;   // 8 bf16 (4 VGPRs) - MFMA A/B frag
typedef __attribute__((ext_vector_type(4))) float fx4;    // MFMA C/D frag

#define MFMA16(a,b,c) __builtin_amdgcn_mfma_f32_16x16x32_bf16((a),(b),(c),0,0,0)

__device__ __forceinline__ unsigned short bfc(float x){
  return __builtin_bit_cast(unsigned short, __float2bfloat16(x));
}
__device__ __forceinline__ unsigned pack2(float a, float b){
  return (unsigned)bfc(a) | ((unsigned)bfc(b) << 16);
}

// load 8 contiguous floats, convert to bf16 frag
__device__ __forceinline__ bfx8 cvt8(const float* p){
  const float4* q = (const float4*)p;
  float4 a = q[0], b = q[1];
  bfx8 r;
  r[0]=(short)bfc(a.x); r[1]=(short)bfc(a.y); r[2]=(short)bfc(a.z); r[3]=(short)bfc(a.w);
  r[4]=(short)bfc(b.x); r[5]=(short)bfc(b.y); r[6]=(short)bfc(b.z); r[7]=(short)bfc(b.w);
  return r;
}

// async global->LDS, 16B per lane; dest is wave-uniform base + lane*16
__device__ __forceinline__ void g2l16(const void* g, void* l){
  __builtin_amdgcn_global_load_lds((const __attribute__((address_space(1))) unsigned*)g,
                                   (__attribute__((address_space(3))) unsigned*)l, 16, 0, 0);
}

#define SCL 0.04508422002778f   /* log2(e)/sqrt(1024) */

// ---------- kernel 1: Wo -> bf16 ; mask -> pair-AND-masks ----------
// em[n][kt][q][w] (w = g*8 + mt*2 + t): u32 AND-mask for the bf16 pair
// (kv, kv+1) with kv = mt*16 + g*4 + t*2 -- exactly the order flash packs P.
__global__ __launch_bounds__(256) void pack_k(const int* __restrict__ M, const float* __restrict__ Wo,
                                              unsigned* __restrict__ em,
                                              unsigned short* __restrict__ Wob){
  int bid = blockIdx.x, tid = threadIdx.x;
  if (bid < 512){
    int i = (bid*256 + tid)*8;             // 512 blocks cover 1024*1024 elems
    bfx8 v = cvt8(Wo + i);
    *(bfx8*)(Wob + i) = v;
  } else {
    unsigned idx = (unsigned)(bid - 512)*256u + (unsigned)tid;   // < 2^23
    int w = idx & 31, q = (idx >> 5) & 2047, kt = (idx >> 16) & 31, n = idx >> 21;
    int g = w >> 3, mt = (w >> 1) & 3, t = w & 1;
    int kv = mt*16 + g*4 + t*2;
    const int* src = M + ((size_t)n*2048 + q)*2048 + kt*64 + kv;
    unsigned word = (src[0] != 0 ? 0x0000FFFFu : 0u) | (src[1] != 0 ? 0xFFFF0000u : 0u);
    em[idx] = word;
  }
}

// ---------- kernel 2: projections ----------
// which=0: Vt[nh][64 d][2048 s] = (X@Wv^T)^T ; which=1/2: Kb/Qb[nh][2048 s][64 d]
// Q is pre-scaled by log2(e)/sqrt(EMBED) so flash's exp2 needs no multiply.
__global__ __launch_bounds__(256) void proj_k(const float* __restrict__ Xv, const float* __restrict__ Xk,
                                              const float* __restrict__ Xq,
                                              const float* __restrict__ Wv, const float* __restrict__ Wk,
                                              const float* __restrict__ Wq,
                                              unsigned short* __restrict__ Vt, unsigned short* __restrict__ Kb,
                                              unsigned short* __restrict__ Qb){
  int bid = blockIdx.x;
  int which = bid >> 10;                   // 0=v,1=k,2=q
  int r = bid & 1023;
  int nh = r >> 4, sb = r & 15;
  int n = nh >> 4, h = nh & 15;
  int tid = threadIdx.x, l = tid & 63, wv = tid >> 6, g = l >> 4, j = l & 15;
  const float* X = (which==0) ? Xv : ((which==1) ? Xk : Xq);
  const float* W = (which==0) ? Wv : ((which==1) ? Wk : Wq);
  int s0 = sb*128 + wv*32;
  size_t xbase = (size_t)n*2048*1024 + (size_t)h*64;   // X[n][s][h*64+d]

  if (which){
    // C[m=s][n=e]: A = X rows (s x d), B = W rows (e x d)  -> Kb/Qb[s][e]
    float sc = (which==2) ? SCL : 1.0f;
    bfx8 bw[4][2];
    for (int nt=0;nt<4;++nt) for (int ks=0;ks<2;++ks)
      bw[nt][ks] = cvt8(W + (nt*16 + j)*64 + ks*32 + g*8);
    bfx8 ax[2][2];
    for (int mt=0;mt<2;++mt){
      const float* xp = X + xbase + (size_t)(s0 + mt*16 + j)*1024;
      for (int ks=0;ks<2;++ks) ax[mt][ks] = cvt8(xp + ks*32 + g*8);
    }
    fx4 acc[2][4];
    for (int mt=0;mt<2;++mt) for (int nt=0;nt<4;++nt) acc[mt][nt] = (fx4){0.f,0.f,0.f,0.f};
    for (int mt=0;mt<2;++mt) for (int nt=0;nt<4;++nt) for (int ks=0;ks<2;++ks)
      acc[mt][nt] = MFMA16(ax[mt][ks], bw[nt][ks], acc[mt][nt]);
    unsigned short* O = ((which==1) ? Kb : Qb) + (size_t)nh*2048*64;
    for (int mt=0;mt<2;++mt) for (int nt=0;nt<4;++nt) for (int rr=0;rr<4;++rr){
      int s = s0 + mt*16 + g*4 + rr, e = nt*16 + j;
      O[(size_t)s*64 + e] = bfc(acc[mt][nt][rr]*sc);
    }
  } else {
    // C[m=e][n=s]: A = Wv rows (e x d), B = X rows (s x d) -> Vt[e][s]
    bfx8 aw[4][2];
    for (int mt=0;mt<4;++mt) for (int ks=0;ks<2;++ks)
      aw[mt][ks] = cvt8(W + (mt*16 + j)*64 + ks*32 + g*8);
    bfx8 bx[2][2];
    for (int nt=0;nt<2;++nt){
      const float* xp = X + xbase + (size_t)(s0 + nt*16 + j)*1024;
      for (int ks=0;ks<2;++ks) bx[nt][ks] = cvt8(xp + ks*32 + g*8);
    }
    fx4 acc[4][2];
    for (int mt=0;mt<4;++mt) for (int nt=0;nt<2;++nt) acc[mt][nt] = (fx4){0.f,0.f,0.f,0.f};
    for (int mt=0;mt<4;++mt) for (int nt=0;nt<2;++nt) for (int ks=0;ks<2;++ks)
      acc[mt][nt] = MFMA16(aw[mt][ks], bx[nt][ks], acc[mt][nt]);
    unsigned short* O = Vt + (size_t)nh*64*2048;
    for (int mt=0;mt<4;++mt) for (int nt=0;nt<2;++nt) for (int rr=0;rr<4;++rr){
      int d = mt*16 + g*4 + rr, s = s0 + nt*16 + j;
      O[(size_t)d*2048 + s] = bfc(acc[mt][nt][rr]);
    }
  }
}

// ---------- kernel 3: flash attention ----------
// grid: 64 nh x 16 qblocks of 128 rows. 8 waves x 16 q-rows. KVBLK=64, double-buffered.
// swapped QK^T: St = mfma(K, Q) -> lane holds 16 kv scores of one q-row (q = lane&15)
// Q pre-scaled by log2(e)/32 -> |logit2| small, exp2 directly; mask applied as
// precomputed u32 AND on packed bf16 pairs; lsum via ones-MFMA (acc5).
__global__ __launch_bounds__(512, 6) void flash_k(const unsigned short* __restrict__ Qb,
                                                  const unsigned short* __restrict__ Kb,
                                                  const unsigned short* __restrict__ Vt,
                                                  const unsigned* __restrict__ em,
                                                  unsigned short* __restrict__ AO){
  __shared__ short lK[2][64*64];    // [buf][kv row][128B], 16B-chunk XOR swizzled by (row&7)
  __shared__ short lV[2][64*64];    // [buf][d  row][128B], same swizzle
  __shared__ unsigned lP[8][512];   // per-wave P tile [q 16][kv 64] bf16, swizzled
  int tid = threadIdx.x;
  int l = tid & 63, wv = tid >> 6, g = l >> 4, j = l & 15;
  int bid = blockIdx.x;
  int nh = bid >> 4, qb = bid & 15;
  int n = nh >> 4, h = nh & 15;
  const unsigned short* Qp = Qb + (size_t)nh*2048*64;
  const unsigned short* Kp = Kb + (size_t)nh*2048*64;
  const unsigned short* Vp = Vt + (size_t)nh*64*2048;
  int q = qb*128 + wv*16 + j;
  bfx8 qf[2];
  qf[0] = *(const bfx8*)(Qp + (size_t)q*64 + g*8);
  qf[1] = *(const bfx8*)(Qp + (size_t)q*64 + 32 + g*8);
  bfx8 ones;
  #pragma unroll
  for (int i=0;i<8;++i) ones[i] = (short)0x3F80;   // bf16 1.0
  fx4 accO[4];
  #pragma unroll
  for (int mt=0;mt<4;++mt) accO[mt] = (fx4){0.f,0.f,0.f,0.f};
  fx4 acc5 = (fx4){0.f,0.f,0.f,0.f};               // row-sum accumulator
  const int swz = (j & 7) << 4;

  // per-lane mask pointer: words [g*8 .. g*8+7] of em[n][kt][q][32]
  const uint4* ep = (const uint4*)em + ((size_t)n*524288 + (size_t)q*8 + g*2);
  // per-kt stride in uint4 units: 2048*32/4 = 16384

  // staging: 8 waves cover the 64x64 K tile and V tile; 1 g2l16 each per lane
  int sidx = wv*64 + l;                     // 0..511, 16B chunks
  int srow = sidx >> 3, scs = (sidx & 7) ^ (srow & 7);
  const unsigned short* Ksrc = Kp + (size_t)srow*64 + scs*8;
  const unsigned short* Vsrc = Vp + (size_t)srow*2048 + scs*8;

  #define STAGE(b, kt) do { \
    g2l16(Ksrc + (size_t)(kt)*4096, (char*)lK[b] + sidx*16); \
    g2l16(Vsrc + (size_t)(kt)*64,   (char*)lV[b] + sidx*16); \
  } while(0)

  STAGE(0, 0);
  __syncthreads();
  uint4 mca = ep[0], mcb = ep[1];
  int b = 0;

  for (int kt = 0; kt < 32; ++kt){
    uint4 mna = mca, mnb = mcb;
    if (kt < 31){
      STAGE(b^1, kt+1);
      mna = ep[(size_t)(kt+1)*16384];
      mnb = ep[(size_t)(kt+1)*16384 + 1];
    }
    // QK^T
    fx4 st[4];
    #pragma unroll
    for (int mt=0;mt<4;++mt){
      fx4 z = (fx4){0.f,0.f,0.f,0.f};
      #pragma unroll
      for (int ks=0;ks<2;++ks){
        bfx8 kf = *(const bfx8*)((const char*)lK[b] + (mt*16+j)*128 + ((ks*64 + g*16) ^ swz));
        z = MFMA16(kf, qf[ks], z);
      }
      st[mt] = z;
    }
    // exp2 (no max, no per-score mask ops)
    float p[16];
    #pragma unroll
    for (int mt=0;mt<4;++mt)
      #pragma unroll
      for (int rr=0;rr<4;++rr)
        p[mt*4+rr] = __builtin_amdgcn_exp2f(st[mt][rr]);
    // pack to bf16 pairs, AND with precomputed pair-masks, write per-wave LDS
    unsigned* Pb = lP[wv];
    {
      unsigned mw0[4] = {mca.x, mca.y, mca.z, mca.w};
      unsigned mw1[4] = {mcb.x, mcb.y, mcb.z, mcb.w};
      #pragma unroll
      for (int mt=0;mt<4;++mt){
        unsigned w0 = pack2(p[mt*4+0], p[mt*4+1]);
        unsigned w1 = pack2(p[mt*4+2], p[mt*4+3]);
        w0 &= (mt<2) ? mw0[mt*2+0] : mw1[(mt-2)*2+0];
        w1 &= (mt<2) ? mw0[mt*2+1] : mw1[(mt-2)*2+1];
        int b0 = mt*32 + g*8;
        int addr = j*128 + ((((b0 >> 4)) ^ (j & 7)) << 4) + (b0 & 15);
        uint2 w; w.x = w0; w.y = w1;
        *(uint2*)((char*)Pb + addr) = w;
      }
    }
    bfx8 pf[2];
    #pragma unroll
    for (int k2=0;k2<2;++k2){
      int boff = k2*64 + g*16;
      int addr = j*128 + ((((boff>>4)) ^ (j&7)) << 4);
      pf[k2] = *(const bfx8*)((const char*)Pb + addr);
    }
    // out^T = V^T * P^T ; acc5 += ones * P (row sums)
    #pragma unroll
    for (int mt=0;mt<4;++mt)
      #pragma unroll
      for (int k2=0;k2<2;++k2){
        bfx8 vf = *(const bfx8*)((const char*)lV[b] + (mt*16+j)*128 + ((k2*64 + g*16) ^ swz));
        accO[mt] = MFMA16(vf, pf[k2], accO[mt]);
      }
    acc5 = MFMA16(ones, pf[0], acc5);
    acc5 = MFMA16(ones, pf[1], acc5);
    __syncthreads();
    b ^= 1;
    mca = mna; mcb = mnb;
  }
  #undef STAGE

  float inv = 1.0f / acc5[0];
  size_t tok = (size_t)n*2048 + (size_t)qb*128 + wv*16 + j;
  #pragma unroll
  for (int mt=0;mt<4;++mt){
    ushort4 o;
    o.x = bfc(accO[mt][0]*inv); o.y = bfc(accO[mt][1]*inv);
    o.z = bfc(accO[mt][2]*inv); o.w = bfc(accO[mt][3]*inv);
    *(ushort4*)(AO + tok*1024 + h*64 + mt*16 + g*4) = o;
  }
}

// ---------- kernel 4: out = AO(8192x1024 bf16) @ Wo^T + bo (fp32), double-buffered ----------
__global__ __launch_bounds__(256) void gemm_k(const unsigned short* __restrict__ AO,
                                              const unsigned short* __restrict__ Wob,
                                              const float* __restrict__ bo, float* __restrict__ out){
  __shared__ short lA[2][128*32], lB[2][128*32];   // 8KB each buf
  int tid = threadIdx.x, l = tid & 63, wv = tid >> 6, g = l >> 4, j = l & 15;
  int wr = wv >> 1, wc = wv & 1;
  int bid = blockIdx.x;
  int m0 = (bid >> 3)*128, n0 = (bid & 7)*128;
  fx4 acc[4][4];
  #pragma unroll
  for (int mt=0;mt<4;++mt) for (int nt=0;nt<4;++nt) acc[mt][nt] = (fx4){0.f,0.f,0.f,0.f};

  int sbase = wv*128;
  int sidx0 = sbase + l, sidx1 = sbase + 64 + l;
  int srow0 = sidx0 >> 2, sc0 = sidx0 & 3;
  int srow1 = sidx1 >> 2, sc1 = sidx1 & 3;
  const unsigned short* Asrc0 = AO  + (size_t)(m0+srow0)*1024 + sc0*8;
  const unsigned short* Asrc1 = AO  + (size_t)(m0+srow1)*1024 + sc1*8;
  const unsigned short* Bsrc0 = Wob + (size_t)(n0+srow0)*1024 + sc0*8;
  const unsigned short* Bsrc1 = Wob + (size_t)(n0+srow1)*1024 + sc1*8;

  #define GSTAGE(b, kb) do { \
    g2l16(Asrc0 + (kb)*32, (char*)lA[b] + sidx0*16); \
    g2l16(Asrc1 + (kb)*32, (char*)lA[b] + sidx1*16); \
    g2l16(Bsrc0 + (kb)*32, (char*)lB[b] + sidx0*16); \
    g2l16(Bsrc1 + (kb)*32, (char*)lB[b] + sidx1*16); \
  } while(0)

  GSTAGE(0, 0);
  __syncthreads();
  int b = 0;
  for (int kb = 0; kb < 32; ++kb){
    if (kb < 31) GSTAGE(b^1, kb+1);
    bfx8 af[4], bfr[4];
    #pragma unroll
    for (int mt=0;mt<4;++mt) af[mt]  = *(const bfx8*)((const char*)lA[b] + (wr*64 + mt*16 + j)*64 + g*16);
    #pragma unroll
    for (int nt=0;nt<4;++nt) bfr[nt] = *(const bfx8*)((const char*)lB[b] + (wc*64 + nt*16 + j)*64 + g*16);
    #pragma unroll
    for (int mt=0;mt<4;++mt)
      #pragma unroll
      for (int nt=0;nt<4;++nt)
        acc[mt][nt] = MFMA16(af[mt], bfr[nt], acc[mt][nt]);
    __syncthreads();
    b ^= 1;
  }
  #undef GSTAGE

  #pragma unroll
  for (int mt=0;mt<4;++mt)
    #pragma unroll
    for (int nt=0;nt<4;++nt){
      int mm = m0 + wr*64 + mt*16 + g*4;
      int oo = n0 + wc*64 + nt*16 + j;
      float bb = bo[oo];
      #pragma unroll
      for (int rr=0;rr<4;++rr)
        out[(size_t)(mm+rr)*1024 + oo] = acc[mt][nt][rr] + bb;
    }
}

// ---------- launch ----------
extern "C" void kernel_launch(void* const* d_in, const int* in_sizes, int n_in,
                              void* d_out, int out_size, void* d_ws, size_t ws_size,
                              hipStream_t stream){
  const float* V  = (const float*)d_in[0];
  const float* K  = (const float*)d_in[1];
  const float* Q  = (const float*)d_in[2];
  const int*   M  = (const int*)d_in[3];
  const float* Wv = (const float*)d_in[4];
  const float* Wk = (const float*)d_in[5];
  const float* Wq = (const float*)d_in[6];
  const float* Wo = (const float*)d_in[7];
  const float* bo = (const float*)d_in[8];

  char* ws = (char*)d_ws;
  unsigned short* Qb = (unsigned short*)(ws + ((size_t)0  << 20));  // 16MB
  unsigned short* Kb = (unsigned short*)(ws + ((size_t)16 << 20));  // 16MB
  unsigned short* Vt = (unsigned short*)(ws + ((size_t)32 << 20));  // 16MB
  unsigned short* AO = (unsigned short*)(ws + ((size_t)48 << 20));  // 16MB
  unsigned short* Wob = (unsigned short*)(ws + ((size_t)64 << 20)); // 2MB
  unsigned* em = (unsigned*)(ws + ((size_t)66 << 20));              // 32MB

  hipLaunchKernelGGL(pack_k,  dim3(33280), dim3(256), 0, stream, M, Wo, em, Wob);
  hipLaunchKernelGGL(proj_k,  dim3(3072),  dim3(256), 0, stream, V, K, Q, Wv, Wk, Wq, Vt, Kb, Qb);
  hipLaunchKernelGGL(flash_k, dim3(1024),  dim3(512), 0, stream, Qb, Kb, Vt, em, AO);
  hipLaunchKernelGGL(gemm_k,  dim3(512),   dim3(256), 0, stream, AO, Wob, bo, (float*)d_out);
}

// Round 5
// 201.986 us; speedup vs baseline: 1.1339x; 1.1339x over previous
//
#include <hip/hip_runtime.h>
#include <hip/hip_bf16.h>

// ---------- types ----------
typedef __attribute__((ext_vector_type(8))) short bfx8;   // 8 bf16 (4 VGPRs) - MFMA A/B frag
typedef __attribute__((ext_vector_type(4))) float fx4;    // MFMA C/D frag

#define MFMA16(a,b,c) __builtin_amdgcn_mfma_f32_16x16x32_bf16((a),(b),(c),0,0,0)

__device__ __forceinline__ unsigned short bfc(float x){
  return __builtin_bit_cast(unsigned short, __float2bfloat16(x));
}
__device__ __forceinline__ unsigned pack2(float a, float b){
  return (unsigned)bfc(a) | ((unsigned)bfc(b) << 16);
}

// load 8 contiguous floats, convert to bf16 frag
__device__ __forceinline__ bfx8 cvt8(const float* p){
  const float4* q = (const float4*)p;
  float4 a = q[0], b = q[1];
  bfx8 r;
  r[0]=(short)bfc(a.x); r[1]=(short)bfc(a.y); r[2]=(short)bfc(a.z); r[3]=(short)bfc(a.w);
  r[4]=(short)bfc(b.x); r[5]=(short)bfc(b.y); r[6]=(short)bfc(b.z); r[7]=(short)bfc(b.w);
  return r;
}

// async global->LDS, 16B per lane; dest is wave-uniform base + lane*16
__device__ __forceinline__ void g2l16(const void* g, void* l){
  __builtin_amdgcn_global_load_lds((const __attribute__((address_space(1))) unsigned*)g,
                                   (__attribute__((address_space(3))) unsigned*)l, 16, 0, 0);
}

#define SCL 0.04508422002778f   /* log2(e)/sqrt(1024) */

// ---------- kernel 1: mask -> bitmask [n][32][2048] u64 ; Wo -> bf16 ----------
__global__ __launch_bounds__(256) void pack_k(const int* __restrict__ M, const float* __restrict__ Wo,
                                              unsigned long long* __restrict__ mT,
                                              unsigned short* __restrict__ Wob){
  int bid = blockIdx.x, tid = threadIdx.x;
  if (bid < 1024){
    int l = tid & 63, wv = tid >> 6;
    int task = bid*4 + wv;                 // 4096 tasks: n(4) x kt(32) x qchunk(32)
    int n = task >> 10, rem = task & 1023, kt = rem >> 5, qc = rem & 31;
    int qbase = qc*64;
    const int* mp = M + (size_t)n*2048*2048 + (size_t)kt*64 + l;
    unsigned long long myw = 0;
    for (int qq = 0; qq < 64; ++qq){
      unsigned long long b = __ballot(mp[(size_t)(qbase+qq)*2048] != 0);
      if (l == qq) myw = b;
    }
    mT[((size_t)n*32 + kt)*2048 + qbase + l] = myw;
  } else {
    int i = ((bid-1024)*256 + tid)*8;      // 512 blocks cover 1024*1024 elems
    bfx8 v = cvt8(Wo + i);
    *(bfx8*)(Wob + i) = v;
  }
}

// ---------- kernel 2: projections ----------
// which=0: Vt[nh][64 d][2048 s] = (X@Wv^T)^T ; which=1/2: Kb/Qb[nh][2048 s][64 d]
// Q is pre-scaled by log2(e)/sqrt(EMBED) so flash's exp2 needs no multiply.
__global__ __launch_bounds__(256) void proj_k(const float* __restrict__ Xv, const float* __restrict__ Xk,
                                              const float* __restrict__ Xq,
                                              const float* __restrict__ Wv, const float* __restrict__ Wk,
                                              const float* __restrict__ Wq,
                                              unsigned short* __restrict__ Vt, unsigned short* __restrict__ Kb,
                                              unsigned short* __restrict__ Qb){
  int bid = blockIdx.x;
  int which = bid >> 10;                   // 0=v,1=k,2=q
  int r = bid & 1023;
  int nh = r >> 4, sb = r & 15;
  int n = nh >> 4, h = nh & 15;
  int tid = threadIdx.x, l = tid & 63, wv = tid >> 6, g = l >> 4, j = l & 15;
  const float* X = (which==0) ? Xv : ((which==1) ? Xk : Xq);
  const float* W = (which==0) ? Wv : ((which==1) ? Wk : Wq);
  int s0 = sb*128 + wv*32;
  size_t xbase = (size_t)n*2048*1024 + (size_t)h*64;   // X[n][s][h*64+d]

  if (which){
    // C[m=s][n=e]: A = X rows (s x d), B = W rows (e x d)  -> Kb/Qb[s][e]
    float sc = (which==2) ? SCL : 1.0f;
    bfx8 bw[4][2];
    for (int nt=0;nt<4;++nt) for (int ks=0;ks<2;++ks)
      bw[nt][ks] = cvt8(W + (nt*16 + j)*64 + ks*32 + g*8);
    bfx8 ax[2][2];
    for (int mt=0;mt<2;++mt){
      const float* xp = X + xbase + (size_t)(s0 + mt*16 + j)*1024;
      for (int ks=0;ks<2;++ks) ax[mt][ks] = cvt8(xp + ks*32 + g*8);
    }
    fx4 acc[2][4];
    for (int mt=0;mt<2;++mt) for (int nt=0;nt<4;++nt) acc[mt][nt] = (fx4){0.f,0.f,0.f,0.f};
    for (int mt=0;mt<2;++mt) for (int nt=0;nt<4;++nt) for (int ks=0;ks<2;++ks)
      acc[mt][nt] = MFMA16(ax[mt][ks], bw[nt][ks], acc[mt][nt]);
    unsigned short* O = ((which==1) ? Kb : Qb) + (size_t)nh*2048*64;
    for (int mt=0;mt<2;++mt) for (int nt=0;nt<4;++nt) for (int rr=0;rr<4;++rr){
      int s = s0 + mt*16 + g*4 + rr, e = nt*16 + j;
      O[(size_t)s*64 + e] = bfc(acc[mt][nt][rr]*sc);
    }
  } else {
    // C[m=e][n=s]: A = Wv rows (e x d), B = X rows (s x d) -> Vt[e][s]
    bfx8 aw[4][2];
    for (int mt=0;mt<4;++mt) for (int ks=0;ks<2;++ks)
      aw[mt][ks] = cvt8(W + (mt*16 + j)*64 + ks*32 + g*8);
    bfx8 bx[2][2];
    for (int nt=0;nt<2;++nt){
      const float* xp = X + xbase + (size_t)(s0 + nt*16 + j)*1024;
      for (int ks=0;ks<2;++ks) bx[nt][ks] = cvt8(xp + ks*32 + g*8);
    }
    fx4 acc[4][2];
    for (int mt=0;mt<4;++mt) for (int nt=0;nt<2;++nt) acc[mt][nt] = (fx4){0.f,0.f,0.f,0.f};
    for (int mt=0;mt<4;++mt) for (int nt=0;nt<2;++nt) for (int ks=0;ks<2;++ks)
      acc[mt][nt] = MFMA16(aw[mt][ks], bx[nt][ks], acc[mt][nt]);
    unsigned short* O = Vt + (size_t)nh*64*2048;
    for (int mt=0;mt<4;++mt) for (int nt=0;nt<2;++nt) for (int rr=0;rr<4;++rr){
      int d = mt*16 + g*4 + rr, s = s0 + nt*16 + j;
      O[(size_t)d*2048 + s] = bfc(acc[mt][nt][rr]);
    }
  }
}

// ---------- kernel 3: flash attention (dual q-group waves) ----------
// grid: 64 nh x 8 qblocks of 256 rows. 8 waves x 32 q-rows (2 groups of 16).
// Every K/V LDS fragment read feeds 2 MFMAs (one per q-group) -> LDS traffic
// per unit work ~1.8x lower than single-group. KVBLK=64, double-buffered.
// swapped QK^T: St = mfma(K, Q) -> lane holds 16 kv scores of one q-row.
// Q pre-scaled by log2(e)/32; mask = u64 bitmask select to -inf before exp2;
// lsum via ones-MFMA.
__global__ __launch_bounds__(512, 4) void flash_k(const unsigned short* __restrict__ Qb,
                                                  const unsigned short* __restrict__ Kb,
                                                  const unsigned short* __restrict__ Vt,
                                                  const unsigned long long* __restrict__ mT,
                                                  unsigned short* __restrict__ AO){
  __shared__ short lK[2][64*64];    // [buf][kv row][128B], 16B-chunk XOR swizzled by (row&7)
  __shared__ short lV[2][64*64];    // [buf][d  row][128B], same swizzle
  __shared__ unsigned lP[8][1024];  // per-wave P: [group][q 16][kv 64] bf16, swizzled
  int tid = threadIdx.x;
  int l = tid & 63, wv = tid >> 6, g = l >> 4, j = l & 15;
  int bid = blockIdx.x;
  int nh = bid >> 3, qb = bid & 7;
  int n = nh >> 4, h = nh & 15;
  const unsigned short* Qp = Qb + (size_t)nh*2048*64;
  const unsigned short* Kp = Kb + (size_t)nh*2048*64;
  const unsigned short* Vp = Vt + (size_t)nh*64*2048;
  int q0 = qb*256 + wv*32 + j;         // group 0 q-row
  // group 1 q-row = q0 + 16
  bfx8 qf0[2], qf1[2];
  qf0[0] = *(const bfx8*)(Qp + (size_t)q0*64 + g*8);
  qf0[1] = *(const bfx8*)(Qp + (size_t)q0*64 + 32 + g*8);
  qf1[0] = *(const bfx8*)(Qp + (size_t)(q0+16)*64 + g*8);
  qf1[1] = *(const bfx8*)(Qp + (size_t)(q0+16)*64 + 32 + g*8);
  bfx8 ones;
  #pragma unroll
  for (int i=0;i<8;++i) ones[i] = (short)0x3F80;   // bf16 1.0
  fx4 accO0[4], accO1[4];
  #pragma unroll
  for (int mt=0;mt<4;++mt){ accO0[mt] = (fx4){0.f,0.f,0.f,0.f}; accO1[mt] = (fx4){0.f,0.f,0.f,0.f}; }
  fx4 acc5a = (fx4){0.f,0.f,0.f,0.f};              // row-sum accumulators
  fx4 acc5b = (fx4){0.f,0.f,0.f,0.f};
  const int swz = (j & 7) << 4;
  const unsigned long long* mrow0 = mT + (size_t)n*32*2048 + q0;   // [+16 for group 1]

  // staging: 8 waves cover the 64x64 K tile and V tile; 1 g2l16 each per lane
  int sidx = wv*64 + l;                     // 0..511, 16B chunks
  int srow = sidx >> 3, scs = (sidx & 7) ^ (srow & 7);
  const unsigned short* Ksrc = Kp + (size_t)srow*64 + scs*8;
  const unsigned short* Vsrc = Vp + (size_t)srow*2048 + scs*8;

  #define STAGE(b, kt) do { \
    g2l16(Ksrc + (size_t)(kt)*4096, (char*)lK[b] + sidx*16); \
    g2l16(Vsrc + (size_t)(kt)*64,   (char*)lV[b] + sidx*16); \
  } while(0)

  STAGE(0, 0);
  __syncthreads();
  int b = 0;

  for (int kt = 0; kt < 32; ++kt){
    if (kt < 31) STAGE(b^1, kt+1);
    unsigned long long mw0 = mrow0[(size_t)kt*2048];
    unsigned long long mw1 = mrow0[(size_t)kt*2048 + 16];
    // QK^T for both groups, sharing each K fragment
    fx4 st0[4], st1[4];
    #pragma unroll
    for (int mt=0;mt<4;++mt){
      fx4 z0 = (fx4){0.f,0.f,0.f,0.f}, z1 = (fx4){0.f,0.f,0.f,0.f};
      #pragma unroll
      for (int ks=0;ks<2;++ks){
        bfx8 kf = *(const bfx8*)((const char*)lK[b] + (mt*16+j)*128 + ((ks*64 + g*16) ^ swz));
        z0 = MFMA16(kf, qf0[ks], z0);
        z1 = MFMA16(kf, qf1[ks], z1);
      }
      st0[mt] = z0; st1[mt] = z1;
    }
    unsigned* Pb = lP[wv];
    // group 0: mask -> exp2 -> pack to LDS
    #pragma unroll
    for (int mt=0;mt<4;++mt){
      unsigned mq = (unsigned)(mw0 >> (mt*16 + g*4)) & 0xFu;
      float p0 = __builtin_amdgcn_exp2f(((mq>>0)&1u) ? st0[mt][0] : -1e30f);
      float p1 = __builtin_amdgcn_exp2f(((mq>>1)&1u) ? st0[mt][1] : -1e30f);
      float p2 = __builtin_amdgcn_exp2f(((mq>>2)&1u) ? st0[mt][2] : -1e30f);
      float p3 = __builtin_amdgcn_exp2f(((mq>>3)&1u) ? st0[mt][3] : -1e30f);
      int b0 = mt*32 + g*8;
      int addr = j*128 + ((((b0 >> 4)) ^ (j & 7)) << 4) + (b0 & 15);
      uint2 w; w.x = pack2(p0, p1); w.y = pack2(p2, p3);
      *(uint2*)((char*)Pb + addr) = w;
    }
    // group 1
    #pragma unroll
    for (int mt=0;mt<4;++mt){
      unsigned mq = (unsigned)(mw1 >> (mt*16 + g*4)) & 0xFu;
      float p0 = __builtin_amdgcn_exp2f(((mq>>0)&1u) ? st1[mt][0] : -1e30f);
      float p1 = __builtin_amdgcn_exp2f(((mq>>1)&1u) ? st1[mt][1] : -1e30f);
      float p2 = __builtin_amdgcn_exp2f(((mq>>2)&1u) ? st1[mt][2] : -1e30f);
      float p3 = __builtin_amdgcn_exp2f(((mq>>3)&1u) ? st1[mt][3] : -1e30f);
      int b0 = mt*32 + g*8;
      int addr = 2048 + j*128 + ((((b0 >> 4)) ^ (j & 7)) << 4) + (b0 & 15);
      uint2 w; w.x = pack2(p0, p1); w.y = pack2(p2, p3);
      *(uint2*)((char*)Pb + addr) = w;
    }
    // read back P fragments for PV
    bfx8 pf0[2], pf1[2];
    #pragma unroll
    for (int k2=0;k2<2;++k2){
      int boff = k2*64 + g*16;
      int addr = j*128 + ((((boff>>4)) ^ (j&7)) << 4);
      pf0[k2] = *(const bfx8*)((const char*)Pb + addr);
      pf1[k2] = *(const bfx8*)((const char*)Pb + 2048 + addr);
    }
    // PV for both groups, sharing each V fragment ; row sums via ones-MFMA
    #pragma unroll
    for (int mt=0;mt<4;++mt)
      #pragma unroll
      for (int k2=0;k2<2;++k2){
        bfx8 vf = *(const bfx8*)((const char*)lV[b] + (mt*16+j)*128 + ((k2*64 + g*16) ^ swz));
        accO0[mt] = MFMA16(vf, pf0[k2], accO0[mt]);
        accO1[mt] = MFMA16(vf, pf1[k2], accO1[mt]);
      }
    acc5a = MFMA16(ones, pf0[0], acc5a);
    acc5a = MFMA16(ones, pf0[1], acc5a);
    acc5b = MFMA16(ones, pf1[0], acc5b);
    acc5b = MFMA16(ones, pf1[1], acc5b);
    __syncthreads();
    b ^= 1;
  }
  #undef STAGE

  float inv0 = 1.0f / acc5a[0];
  float inv1 = 1.0f / acc5b[0];
  size_t tok0 = (size_t)n*2048 + (size_t)qb*256 + wv*32 + j;
  #pragma unroll
  for (int mt=0;mt<4;++mt){
    ushort4 o;
    o.x = bfc(accO0[mt][0]*inv0); o.y = bfc(accO0[mt][1]*inv0);
    o.z = bfc(accO0[mt][2]*inv0); o.w = bfc(accO0[mt][3]*inv0);
    *(ushort4*)(AO + tok0*1024 + h*64 + mt*16 + g*4) = o;
    ushort4 o1;
    o1.x = bfc(accO1[mt][0]*inv1); o1.y = bfc(accO1[mt][1]*inv1);
    o1.z = bfc(accO1[mt][2]*inv1); o1.w = bfc(accO1[mt][3]*inv1);
    *(ushort4*)(AO + (tok0+16)*1024 + h*64 + mt*16 + g*4) = o1;
  }
}

// ---------- kernel 4: out = AO(8192x1024 bf16) @ Wo^T + bo (fp32), double-buffered ----------
__global__ __launch_bounds__(256) void gemm_k(const unsigned short* __restrict__ AO,
                                              const unsigned short* __restrict__ Wob,
                                              const float* __restrict__ bo, float* __restrict__ out){
  __shared__ short lA[2][128*32], lB[2][128*32];   // 8KB each buf
  int tid = threadIdx.x, l = tid & 63, wv = tid >> 6, g = l >> 4, j = l & 15;
  int wr = wv >> 1, wc = wv & 1;
  int bid = blockIdx.x;
  int m0 = (bid >> 3)*128, n0 = (bid & 7)*128;
  fx4 acc[4][4];
  #pragma unroll
  for (int mt=0;mt<4;++mt) for (int nt=0;nt<4;++nt) acc[mt][nt] = (fx4){0.f,0.f,0.f,0.f};

  int sbase = wv*128;
  int sidx0 = sbase + l, sidx1 = sbase + 64 + l;
  int srow0 = sidx0 >> 2, sc0 = sidx0 & 3;
  int srow1 = sidx1 >> 2, sc1 = sidx1 & 3;
  const unsigned short* Asrc0 = AO  + (size_t)(m0+srow0)*1024 + sc0*8;
  const unsigned short* Asrc1 = AO  + (size_t)(m0+srow1)*1024 + sc1*8;
  const unsigned short* Bsrc0 = Wob + (size_t)(n0+srow0)*1024 + sc0*8;
  const unsigned short* Bsrc1 = Wob + (size_t)(n0+srow1)*1024 + sc1*8;

  #define GSTAGE(b, kb) do { \
    g2l16(Asrc0 + (kb)*32, (char*)lA[b] + sidx0*16); \
    g2l16(Asrc1 + (kb)*32, (char*)lA[b] + sidx1*16); \
    g2l16(Bsrc0 + (kb)*32, (char*)lB[b] + sidx0*16); \
    g2l16(Bsrc1 + (kb)*32, (char*)lB[b] + sidx1*16); \
  } while(0)

  GSTAGE(0, 0);
  __syncthreads();
  int b = 0;
  for (int kb = 0; kb < 32; ++kb){
    if (kb < 31) GSTAGE(b^1, kb+1);
    bfx8 af[4], bfr[4];
    #pragma unroll
    for (int mt=0;mt<4;++mt) af[mt]  = *(const bfx8*)((const char*)lA[b] + (wr*64 + mt*16 + j)*64 + g*16);
    #pragma unroll
    for (int nt=0;nt<4;++nt) bfr[nt] = *(const bfx8*)((const char*)lB[b] + (wc*64 + nt*16 + j)*64 + g*16);
    #pragma unroll
    for (int mt=0;mt<4;++mt)
      #pragma unroll
      for (int nt=0;nt<4;++nt)
        acc[mt][nt] = MFMA16(af[mt], bfr[nt], acc[mt][nt]);
    __syncthreads();
    b ^= 1;
  }
  #undef GSTAGE

  #pragma unroll
  for (int mt=0;mt<4;++mt)
    #pragma unroll
    for (int nt=0;nt<4;++nt){
      int mm = m0 + wr*64 + mt*16 + g*4;
      int oo = n0 + wc*64 + nt*16 + j;
      float bb = bo[oo];
      #pragma unroll
      for (int rr=0;rr<4;++rr)
        out[(size_t)(mm+rr)*1024 + oo] = acc[mt][nt][rr] + bb;
    }
}

// ---------- launch ----------
extern "C" void kernel_launch(void* const* d_in, const int* in_sizes, int n_in,
                              void* d_out, int out_size, void* d_ws, size_t ws_size,
                              hipStream_t stream){
  const float* V  = (const float*)d_in[0];
  const float* K  = (const float*)d_in[1];
  const float* Q  = (const float*)d_in[2];
  const int*   M  = (const int*)d_in[3];
  const float* Wv = (const float*)d_in[4];
  const float* Wk = (const float*)d_in[5];
  const float* Wq = (const float*)d_in[6];
  const float* Wo = (const float*)d_in[7];
  const float* bo = (const float*)d_in[8];

  char* ws = (char*)d_ws;
  unsigned short* Qb = (unsigned short*)(ws + ((size_t)0  << 20));  // 16MB
  unsigned short* Kb = (unsigned short*)(ws + ((size_t)16 << 20));  // 16MB
  unsigned short* Vt = (unsigned short*)(ws + ((size_t)32 << 20));  // 16MB
  unsigned short* AO = (unsigned short*)(ws + ((size_t)48 << 20));  // 16MB
  unsigned long long* mT = (unsigned long long*)(ws + ((size_t)64 << 20)); // 2MB
  unsigned short* Wob = (unsigned short*)(ws + ((size_t)66 << 20)); // 2MB

  hipLaunchKernelGGL(pack_k,  dim3(1536), dim3(256), 0, stream, M, Wo, mT, Wob);
  hipLaunchKernelGGL(proj_k,  dim3(3072), dim3(256), 0, stream, V, K, Q, Wv, Wk, Wq, Vt, Kb, Qb);
  hipLaunchKernelGGL(flash_k, dim3(512),  dim3(512), 0, stream, Qb, Kb, Vt, mT, AO);
  hipLaunchKernelGGL(gemm_k,  dim3(512),  dim3(256), 0, stream, AO, Wob, bo, (float*)d_out);
}

// Round 7
// 192.797 us; speedup vs baseline: 1.1879x; 1.0477x over previous
//
#include <hip/hip_runtime.h>
#include <hip/hip_bf16.h>

// ---------- types ----------
typedef __attribute__((ext_vector_type(8))) short bfx8;    // 8 bf16 (4 VGPRs) MFMA A/B frag
typedef __attribute__((ext_vector_type(4))) float fx4;     // 16x16 C/D frag
typedef __attribute__((ext_vector_type(16))) float f32x16; // 32x32 C/D frag
typedef __attribute__((ext_vector_type(4))) unsigned u32x4;

#define MFMA16(a,b,c) __builtin_amdgcn_mfma_f32_16x16x32_bf16((a),(b),(c),0,0,0)
#define MFMA32(a,b,c) __builtin_amdgcn_mfma_f32_32x32x16_bf16((a),(b),(c),0,0,0)

__device__ __forceinline__ unsigned short bfc(float x){
  return __builtin_bit_cast(unsigned short, __float2bfloat16(x));
}
__device__ __forceinline__ unsigned pack2(float a, float b){
  return (unsigned)bfc(a) | ((unsigned)bfc(b) << 16);
}
__device__ __forceinline__ bfx8 cvt8(const float* p){
  const float4* q = (const float4*)p;
  float4 a = q[0], b = q[1];
  bfx8 r;
  r[0]=(short)bfc(a.x); r[1]=(short)bfc(a.y); r[2]=(short)bfc(a.z); r[3]=(short)bfc(a.w);
  r[4]=(short)bfc(b.x); r[5]=(short)bfc(b.y); r[6]=(short)bfc(b.z); r[7]=(short)bfc(b.w);
  return r;
}
__device__ __forceinline__ void g2l16(const void* g, void* l){
  __builtin_amdgcn_global_load_lds((const __attribute__((address_space(1))) unsigned*)g,
                                   (__attribute__((address_space(3))) unsigned*)l, 16, 0, 0);
}
// masked exp2: bit (pos) of mws selects exp2(z) or 0
__device__ __forceinline__ float mexp(float zv, unsigned mws, int pos){
  float e = __builtin_amdgcn_exp2f(zv);
  unsigned msk = (unsigned)(((int)(mws << (31-pos))) >> 31);
  return __builtin_bit_cast(float, __builtin_bit_cast(unsigned, e) & msk);
}
__device__ __forceinline__ f32x16 zero16(){
  f32x16 z;
  #pragma unroll
  for (int i=0;i<16;++i) z[i] = 0.f;
  return z;
}

#define SCL 0.04508422002778f   /* log2(e)/sqrt(1024) */

// ---------- kernel 1: projections + mask bitpack + Wo cast (merged) ----------
// bid<3072: proj. which=0: Vt[nh][64 d][2048 s]; 1/2: Kb/Qb[nh][2048 s][64 d] (Q pre-scaled)
// bid>=3072: pid<1024 -> mask u64 bitpack mT[n][32][2048]; else Wo->bf16
__global__ __launch_bounds__(256) void prep_k(const float* __restrict__ Xv, const float* __restrict__ Xk,
                                              const float* __restrict__ Xq,
                                              const float* __restrict__ Wv, const float* __restrict__ Wk,
                                              const float* __restrict__ Wq,
                                              const int* __restrict__ M, const float* __restrict__ Wo,
                                              unsigned short* __restrict__ Vt, unsigned short* __restrict__ Kb,
                                              unsigned short* __restrict__ Qb,
                                              unsigned long long* __restrict__ mT,
                                              unsigned short* __restrict__ Wob){
  int bid = blockIdx.x;
  int tid = threadIdx.x, l = tid & 63, wv = tid >> 6, g = l >> 4, j = l & 15;
  if (bid >= 3072){
    int pid = bid - 3072;
    if (pid < 1024){
      int task = pid*4 + wv;               // 4096 tasks: n(4) x kt(32) x qchunk(32)
      int n = task >> 10, rem = task & 1023, kt = rem >> 5, qc = rem & 31;
      int qbase = qc*64;
      const int* mp = M + (size_t)n*2048*2048 + (size_t)kt*64 + l;
      unsigned long long myw = 0;
      for (int qq = 0; qq < 64; ++qq){
        unsigned long long b = __ballot(mp[(size_t)(qbase+qq)*2048] != 0);
        if (l == qq) myw = b;
      }
      mT[((size_t)n*32 + kt)*2048 + qbase + l] = myw;
    } else {
      int i = ((pid-1024)*256 + tid)*8;    // 512 blocks cover 1024*1024
      bfx8 v = cvt8(Wo + i);
      *(bfx8*)(Wob + i) = v;
    }
    return;
  }
  int which = bid >> 10;                   // 0=v,1=k,2=q
  int r = bid & 1023;
  int nh = r >> 4, sb = r & 15;
  int n = nh >> 4, h = nh & 15;
  const float* X = (which==0) ? Xv : ((which==1) ? Xk : Xq);
  const float* W = (which==0) ? Wv : ((which==1) ? Wk : Wq);
  int s0 = sb*128 + wv*32;
  size_t xbase = (size_t)n*2048*1024 + (size_t)h*64;

  if (which){
    float sc = (which==2) ? SCL : 1.0f;
    bfx8 bw[4][2];
    for (int nt=0;nt<4;++nt) for (int ks=0;ks<2;++ks)
      bw[nt][ks] = cvt8(W + (nt*16 + j)*64 + ks*32 + g*8);
    bfx8 ax[2][2];
    for (int mt=0;mt<2;++mt){
      const float* xp = X + xbase + (size_t)(s0 + mt*16 + j)*1024;
      for (int ks=0;ks<2;++ks) ax[mt][ks] = cvt8(xp + ks*32 + g*8);
    }
    fx4 acc[2][4];
    for (int mt=0;mt<2;++mt) for (int nt=0;nt<4;++nt) acc[mt][nt] = (fx4){0.f,0.f,0.f,0.f};
    for (int mt=0;mt<2;++mt) for (int nt=0;nt<4;++nt) for (int ks=0;ks<2;++ks)
      acc[mt][nt] = MFMA16(ax[mt][ks], bw[nt][ks], acc[mt][nt]);
    unsigned short* O = ((which==1) ? Kb : Qb) + (size_t)nh*2048*64;
    for (int mt=0;mt<2;++mt) for (int nt=0;nt<4;++nt) for (int rr=0;rr<4;++rr){
      int s = s0 + mt*16 + g*4 + rr, e = nt*16 + j;
      O[(size_t)s*64 + e] = bfc(acc[mt][nt][rr]*sc);
    }
  } else {
    bfx8 aw[4][2];
    for (int mt=0;mt<4;++mt) for (int ks=0;ks<2;++ks)
      aw[mt][ks] = cvt8(W + (mt*16 + j)*64 + ks*32 + g*8);
    bfx8 bx[2][2];
    for (int nt=0;nt<2;++nt){
      const float* xp = X + xbase + (size_t)(s0 + nt*16 + j)*1024;
      for (int ks=0;ks<2;++ks) bx[nt][ks] = cvt8(xp + ks*32 + g*8);
    }
    fx4 acc[4][2];
    for (int mt=0;mt<4;++mt) for (int nt=0;nt<2;++nt) acc[mt][nt] = (fx4){0.f,0.f,0.f,0.f};
    for (int mt=0;mt<4;++mt) for (int nt=0;nt<2;++nt) for (int ks=0;ks<2;++ks)
      acc[mt][nt] = MFMA16(aw[mt][ks], bx[nt][ks], acc[mt][nt]);
    unsigned short* O = Vt + (size_t)nh*64*2048;
    for (int mt=0;mt<4;++mt) for (int nt=0;nt<2;++nt) for (int rr=0;rr<4;++rr){
      int d = mt*16 + g*4 + rr, s = s0 + nt*16 + j;
      O[(size_t)d*2048 + s] = bfc(acc[mt][nt][rr]);
    }
  }
}

// ---------- kernel 2: flash attention, 32x32 MFMA + shfl P redistribution ----------
// grid: 64 nh x 8 qblocks of 256 rows. 8 waves x 32 q-cols. KVBLK=64 dbuf.
// QK^T: D[kv][q] = mfma32(K, Q); lane (hi,c) holds 16 scores of col q=c
//   (kv = 4hi + (r&3) + 8(r>>2), 2 tiles of 32 kv).
// mask: u64 bitmask, sign-shift select on exp2 output; lsum: f32 adds + final shfl.
// P -> PV B-frag: lane needs kv = 16mm+8hi+i of its q-col; own Wt words hold
//   kv pairs {8a+2b+4hi}; partner-half words fetched with select+shfl_xor(32)+select.
__global__ __launch_bounds__(512, 4) void flash_k(const unsigned short* __restrict__ Qb,
                                                  const unsigned short* __restrict__ Kb,
                                                  const unsigned short* __restrict__ Vt,
                                                  const unsigned long long* __restrict__ mT,
                                                  unsigned short* __restrict__ AO){
  __shared__ short lK[2][64*64];   // [buf][kv row][128B], 16B chunks XOR-swizzled by row&7
  __shared__ short lV[2][64*64];   // [buf][d  row][128B], same swizzle
  int tid = threadIdx.x;
  int l = tid & 63, wv = tid >> 6, hi = l >> 5, c = l & 31;
  int cl7 = c & 7, hi4 = hi*4;
  int bid = blockIdx.x;
  int nh = bid >> 3, qb = bid & 7;
  int n = nh >> 4, h = nh & 15;
  const unsigned short* Qp = Qb + (size_t)nh*131072;
  const unsigned short* Kp = Kb + (size_t)nh*131072;
  const unsigned short* Vp = Vt + (size_t)nh*131072;
  int q = qb*256 + wv*32 + c;
  bfx8 qf[4];
  #pragma unroll
  for (int s=0;s<4;++s) qf[s] = *(const bfx8*)(Qp + (size_t)q*64 + s*16 + hi*8);
  f32x16 accO0 = zero16(), accO1 = zero16();
  float ls = 0.f;
  const unsigned long long* mrow = mT + (size_t)n*65536 + q;
  int rowK0 = c*128;          // byte row offset for rows c    (tile/dt 0)
  int rowK1 = rowK0 + 4096;   // rows 32+c (tile/dt 1)

  // staging: 8 waves cover 64x64 K and V tiles; 1 g2l16 each per lane
  int sidx = wv*64 + l;
  int srow = sidx >> 3, scs = (sidx & 7) ^ (srow & 7);
  const unsigned short* Ksrc = Kp + (size_t)srow*64 + scs*8;
  const unsigned short* Vsrc = Vp + (size_t)srow*2048 + scs*8;

  g2l16(Ksrc, (char*)lK[0] + sidx*16);
  g2l16(Vsrc, (char*)lV[0] + sidx*16);
  __syncthreads();

#define PROC_TILE(zz, mws, TT, VB) do { \
    unsigned Wt[8]; \
    _Pragma("unroll") \
    for (int wi=0; wi<8; ++wi){ \
      const int r0 = 2*wi; \
      const int pos = (r0&3) + 8*(r0>>2); \
      float p0_ = mexp((zz)[r0],   (mws), pos); \
      float p1_ = mexp((zz)[r0+1], (mws), pos+1); \
      ls += p0_ + p1_; \
      Wt[wi] = pack2(p0_, p1_); \
    } \
    _Pragma("unroll") \
    for (int mm=0; mm<2; ++mm){ \
      unsigned xa = hi ? Wt[4*mm+0] : Wt[4*mm+2]; \
      unsigned xb = hi ? Wt[4*mm+1] : Wt[4*mm+3]; \
      unsigned ra = (unsigned)__shfl_xor((int)xa, 32); \
      unsigned rb = (unsigned)__shfl_xor((int)xb, 32); \
      u32x4 pw; \
      pw.x = hi ? ra : Wt[4*mm+0]; \
      pw.y = hi ? rb : Wt[4*mm+1]; \
      pw.z = hi ? Wt[4*mm+2] : ra; \
      pw.w = hi ? Wt[4*mm+3] : rb; \
      bfx8 pb = __builtin_bit_cast(bfx8, pw); \
      const int ch2 = 2*((TT)*2+mm); \
      bfx8 vf0 = *(const bfx8*)((VB) + rowK0 + (((ch2+hi) ^ cl7) << 4)); \
      bfx8 vf1 = *(const bfx8*)((VB) + rowK1 + (((ch2+hi) ^ cl7) << 4)); \
      accO0 = MFMA32(vf0, pb, accO0); \
      accO1 = MFMA32(vf1, pb, accO1); \
    } \
  } while(0)

#define ATTN_ITER(BUF, NBUF, kt) do { \
    if ((kt) < 31){ \
      g2l16(Ksrc + (size_t)((kt)+1)*4096, (char*)lK[NBUF] + sidx*16); \
      g2l16(Vsrc + (size_t)((kt)+1)*64,   (char*)lV[NBUF] + sidx*16); \
    } \
    unsigned long long mw = mrow[(size_t)(kt)*2048]; \
    const char* KB = (const char*)lK[BUF]; \
    const char* VB = (const char*)lV[BUF]; \
    f32x16 z0 = zero16(), z1 = zero16(); \
    _Pragma("unroll") \
    for (int s=0; s<4; ++s){ \
      bfx8 kf0 = *(const bfx8*)(KB + rowK0 + (((2*s+hi) ^ cl7) << 4)); \
      bfx8 kf1 = *(const bfx8*)(KB + rowK1 + (((2*s+hi) ^ cl7) << 4)); \
      z0 = MFMA32(kf0, qf[s], z0); \
      z1 = MFMA32(kf1, qf[s], z1); \
    } \
    unsigned mws0 = ((unsigned)mw) >> hi4; \
    unsigned mws1 = ((unsigned)(mw >> 32)) >> hi4; \
    PROC_TILE(z0, mws0, 0, VB); \
    PROC_TILE(z1, mws1, 1, VB); \
    __syncthreads(); \
  } while(0)

  #pragma unroll 1
  for (int kt2 = 0; kt2 < 32; kt2 += 2){
    ATTN_ITER(0, 1, kt2);
    ATTN_ITER(1, 0, kt2+1);
  }
#undef ATTN_ITER
#undef PROC_TILE

  ls += __shfl_xor(ls, 32);
  float inv = 1.0f / ls;
  unsigned short* aop = AO + ((size_t)n*2048 + q)*1024 + h*64;
  #pragma unroll
  for (int u=0; u<4; ++u){
    int d0 = u*8 + hi4;           // d-local = (r&3) + 8*(r>>2) + 4*hi, r=4u+rr
    ushort4 o;
    o.x = bfc(accO0[4*u+0]*inv); o.y = bfc(accO0[4*u+1]*inv);
    o.z = bfc(accO0[4*u+2]*inv); o.w = bfc(accO0[4*u+3]*inv);
    *(ushort4*)(aop + d0) = o;
    ushort4 o1;
    o1.x = bfc(accO1[4*u+0]*inv); o1.y = bfc(accO1[4*u+1]*inv);
    o1.z = bfc(accO1[4*u+2]*inv); o1.w = bfc(accO1[4*u+3]*inv);
    *(ushort4*)(aop + 32 + d0) = o1;
  }
}

// ---------- kernel 3: out = AO(8192x1024 bf16) @ Wo^T + bo (fp32), double-buffered ----------
__global__ __launch_bounds__(256) void gemm_k(const unsigned short* __restrict__ AO,
                                              const unsigned short* __restrict__ Wob,
                                              const float* __restrict__ bo, float* __restrict__ out){
  __shared__ short lA[2][128*32], lB[2][128*32];
  int tid = threadIdx.x, l = tid & 63, wv = tid >> 6, g = l >> 4, j = l & 15;
  int wr = wv >> 1, wc = wv & 1;
  int bid = blockIdx.x;
  int m0 = (bid >> 3)*128, n0 = (bid & 7)*128;
  fx4 acc[4][4];
  #pragma unroll
  for (int mt=0;mt<4;++mt) for (int nt=0;nt<4;++nt) acc[mt][nt] = (fx4){0.f,0.f,0.f,0.f};

  int sbase = wv*128;
  int sidx0 = sbase + l, sidx1 = sbase + 64 + l;
  int srow0 = sidx0 >> 2, sc0 = sidx0 & 3;
  int srow1 = sidx1 >> 2, sc1 = sidx1 & 3;
  const unsigned short* Asrc0 = AO  + (size_t)(m0+srow0)*1024 + sc0*8;
  const unsigned short* Asrc1 = AO  + (size_t)(m0+srow1)*1024 + sc1*8;
  const unsigned short* Bsrc0 = Wob + (size_t)(n0+srow0)*1024 + sc0*8;
  const unsigned short* Bsrc1 = Wob + (size_t)(n0+srow1)*1024 + sc1*8;

  #define GSTAGE(b, kb) do { \
    g2l16(Asrc0 + (kb)*32, (char*)lA[b] + sidx0*16); \
    g2l16(Asrc1 + (kb)*32, (char*)lA[b] + sidx1*16); \
    g2l16(Bsrc0 + (kb)*32, (char*)lB[b] + sidx0*16); \
    g2l16(Bsrc1 + (kb)*32, (char*)lB[b] + sidx1*16); \
  } while(0)

  GSTAGE(0, 0);
  __syncthreads();
  int b = 0;
  for (int kb = 0; kb < 32; ++kb){
    if (kb < 31) GSTAGE(b^1, kb+1);
    bfx8 af[4], bfr[4];
    #pragma unroll
    for (int mt=0;mt<4;++mt) af[mt]  = *(const bfx8*)((const char*)lA[b] + (wr*64 + mt*16 + j)*64 + g*16);
    #pragma unroll
    for (int nt=0;nt<4;++nt) bfr[nt] = *(const bfx8*)((const char*)lB[b] + (wc*64 + nt*16 + j)*64 + g*16);
    #pragma unroll
    for (int mt=0;mt<4;++mt)
      #pragma unroll
      for (int nt=0;nt<4;++nt)
        acc[mt][nt] = MFMA16(af[mt], bfr[nt], acc[mt][nt]);
    __syncthreads();
    b ^= 1;
  }
  #undef GSTAGE

  #pragma unroll
  for (int mt=0;mt<4;++mt)
    #pragma unroll
    for (int nt=0;nt<4;++nt){
      int mm = m0 + wr*64 + mt*16 + g*4;
      int oo = n0 + wc*64 + nt*16 + j;
      float bb = bo[oo];
      #pragma unroll
      for (int rr=0;rr<4;++rr)
        out[(size_t)(mm+rr)*1024 + oo] = acc[mt][nt][rr] + bb;
    }
}

// ---------- launch ----------
extern "C" void kernel_launch(void* const* d_in, const int* in_sizes, int n_in,
                              void* d_out, int out_size, void* d_ws, size_t ws_size,
                              hipStream_t stream){
  const float* V  = (const float*)d_in[0];
  const float* K  = (const float*)d_in[1];
  const float* Q  = (const float*)d_in[2];
  const int*   M  = (const int*)d_in[3];
  const float* Wv = (const float*)d_in[4];
  const float* Wk = (const float*)d_in[5];
  const float* Wq = (const float*)d_in[6];
  const float* Wo = (const float*)d_in[7];
  const float* bo = (const float*)d_in[8];

  char* ws = (char*)d_ws;
  unsigned short* Qb = (unsigned short*)(ws + ((size_t)0  << 20));  // 16MB
  unsigned short* Kb = (unsigned short*)(ws + ((size_t)16 << 20));  // 16MB
  unsigned short* Vt = (unsigned short*)(ws + ((size_t)32 << 20));  // 16MB
  unsigned short* AO = (unsigned short*)(ws + ((size_t)48 << 20));  // 16MB
  unsigned long long* mT = (unsigned long long*)(ws + ((size_t)64 << 20)); // 2MB
  unsigned short* Wob = (unsigned short*)(ws + ((size_t)66 << 20)); // 2MB

  hipLaunchKernelGGL(prep_k,  dim3(4608), dim3(256), 0, stream,
                     V, K, Q, Wv, Wk, Wq, M, Wo, Vt, Kb, Qb, mT, Wob);
  hipLaunchKernelGGL(flash_k, dim3(512),  dim3(512), 0, stream, Qb, Kb, Vt, mT, AO);
  hipLaunchKernelGGL(gemm_k,  dim3(512),  dim3(256), 0, stream, AO, Wob, bo, (float*)d_out);
}

// Round 8
// 192.126 us; speedup vs baseline: 1.1921x; 1.0035x over previous
//
#include <hip/hip_runtime.h>
#include <hip/hip_bf16.h>

// ---------- types ----------
typedef __attribute__((ext_vector_type(8))) short bfx8;    // 8 bf16 (4 VGPRs) MFMA A/B frag
typedef __attribute__((ext_vector_type(4))) short bfx4;    // 4 bf16 (2 VGPRs) for 32x32x8
typedef __attribute__((ext_vector_type(4))) float fx4;     // 16x16 C/D frag
typedef __attribute__((ext_vector_type(16))) float f32x16; // 32x32 C/D frag

#define MFMA16(a,b,c) __builtin_amdgcn_mfma_f32_16x16x32_bf16((a),(b),(c),0,0,0)
#define MFMA32(a,b,c) __builtin_amdgcn_mfma_f32_32x32x16_bf16((a),(b),(c),0,0,0)

// PV MFMA: 32x32 K=8, A/B = 4 bf16 (2 VGPRs). B[k][q]: k = 4*(lane>>5)+reg -> lane-local P quads.
__device__ __forceinline__ f32x16 mfma32x8(bfx4 a, bfx4 b, f32x16 c){
#if __has_builtin(__builtin_amdgcn_mfma_f32_32x32x8bf16_1k)
  return __builtin_amdgcn_mfma_f32_32x32x8bf16_1k(a, b, c, 0, 0, 0);
#else
  asm("v_mfma_f32_32x32x8_bf16 %0, %1, %2, %0" : "+v"(c) : "v"(a), "v"(b));
  return c;
#endif
}

__device__ __forceinline__ unsigned short bfc(float x){
  return __builtin_bit_cast(unsigned short, __float2bfloat16(x));
}
__device__ __forceinline__ unsigned pack2(float a, float b){
  return (unsigned)bfc(a) | ((unsigned)bfc(b) << 16);
}
__device__ __forceinline__ bfx8 cvt8(const float* p){
  const float4* q = (const float4*)p;
  float4 a = q[0], b = q[1];
  bfx8 r;
  r[0]=(short)bfc(a.x); r[1]=(short)bfc(a.y); r[2]=(short)bfc(a.z); r[3]=(short)bfc(a.w);
  r[4]=(short)bfc(b.x); r[5]=(short)bfc(b.y); r[6]=(short)bfc(b.z); r[7]=(short)bfc(b.w);
  return r;
}
__device__ __forceinline__ void g2l16(const void* g, void* l){
  __builtin_amdgcn_global_load_lds((const __attribute__((address_space(1))) unsigned*)g,
                                   (__attribute__((address_space(3))) unsigned*)l, 16, 0, 0);
}
// masked exp2: bit (pos) of mws selects exp2(z) or 0
__device__ __forceinline__ float mexp(float zv, unsigned mws, int pos){
  float e = __builtin_amdgcn_exp2f(zv);
  unsigned msk = (unsigned)(((int)(mws << (31-pos))) >> 31);
  return __builtin_bit_cast(float, __builtin_bit_cast(unsigned, e) & msk);
}
__device__ __forceinline__ f32x16 zero16(){
  f32x16 z;
  #pragma unroll
  for (int i=0;i<16;++i) z[i] = 0.f;
  return z;
}

#define SCL 0.04508422002778f   /* log2(e)/sqrt(1024) */

// ---------- kernel 1: projections + mask bitpack + Wo cast (merged) ----------
__global__ __launch_bounds__(256) void prep_k(const float* __restrict__ Xv, const float* __restrict__ Xk,
                                              const float* __restrict__ Xq,
                                              const float* __restrict__ Wv, const float* __restrict__ Wk,
                                              const float* __restrict__ Wq,
                                              const int* __restrict__ M, const float* __restrict__ Wo,
                                              unsigned short* __restrict__ Vt, unsigned short* __restrict__ Kb,
                                              unsigned short* __restrict__ Qb,
                                              unsigned long long* __restrict__ mT,
                                              unsigned short* __restrict__ Wob){
  int bid = blockIdx.x;
  int tid = threadIdx.x, l = tid & 63, wv = tid >> 6, g = l >> 4, j = l & 15;
  if (bid >= 3072){
    int pid = bid - 3072;
    if (pid < 1024){
      int task = pid*4 + wv;               // 4096 tasks: n(4) x kt(32) x qchunk(32)
      int n = task >> 10, rem = task & 1023, kt = rem >> 5, qc = rem & 31;
      int qbase = qc*64;
      const int* mp = M + (size_t)n*2048*2048 + (size_t)kt*64 + l;
      unsigned long long myw = 0;
      for (int qq = 0; qq < 64; ++qq){
        unsigned long long b = __ballot(mp[(size_t)(qbase+qq)*2048] != 0);
        if (l == qq) myw = b;
      }
      mT[((size_t)n*32 + kt)*2048 + qbase + l] = myw;
    } else {
      int i = ((pid-1024)*256 + tid)*8;    // 512 blocks cover 1024*1024
      bfx8 v = cvt8(Wo + i);
      *(bfx8*)(Wob + i) = v;
    }
    return;
  }
  int which = bid >> 10;                   // 0=v,1=k,2=q
  int r = bid & 1023;
  int nh = r >> 4, sb = r & 15;
  int n = nh >> 4, h = nh & 15;
  const float* X = (which==0) ? Xv : ((which==1) ? Xk : Xq);
  const float* W = (which==0) ? Wv : ((which==1) ? Wk : Wq);
  int s0 = sb*128 + wv*32;
  size_t xbase = (size_t)n*2048*1024 + (size_t)h*64;

  if (which){
    float sc = (which==2) ? SCL : 1.0f;
    bfx8 bw[4][2];
    for (int nt=0;nt<4;++nt) for (int ks=0;ks<2;++ks)
      bw[nt][ks] = cvt8(W + (nt*16 + j)*64 + ks*32 + g*8);
    bfx8 ax[2][2];
    for (int mt=0;mt<2;++mt){
      const float* xp = X + xbase + (size_t)(s0 + mt*16 + j)*1024;
      for (int ks=0;ks<2;++ks) ax[mt][ks] = cvt8(xp + ks*32 + g*8);
    }
    fx4 acc[2][4];
    for (int mt=0;mt<2;++mt) for (int nt=0;nt<4;++nt) acc[mt][nt] = (fx4){0.f,0.f,0.f,0.f};
    for (int mt=0;mt<2;++mt) for (int nt=0;nt<4;++nt) for (int ks=0;ks<2;++ks)
      acc[mt][nt] = MFMA16(ax[mt][ks], bw[nt][ks], acc[mt][nt]);
    unsigned short* O = ((which==1) ? Kb : Qb) + (size_t)nh*2048*64;
    for (int mt=0;mt<2;++mt) for (int nt=0;nt<4;++nt) for (int rr=0;rr<4;++rr){
      int s = s0 + mt*16 + g*4 + rr, e = nt*16 + j;
      O[(size_t)s*64 + e] = bfc(acc[mt][nt][rr]*sc);
    }
  } else {
    bfx8 aw[4][2];
    for (int mt=0;mt<4;++mt) for (int ks=0;ks<2;++ks)
      aw[mt][ks] = cvt8(W + (mt*16 + j)*64 + ks*32 + g*8);
    bfx8 bx[2][2];
    for (int nt=0;nt<2;++nt){
      const float* xp = X + xbase + (size_t)(s0 + nt*16 + j)*1024;
      for (int ks=0;ks<2;++ks) bx[nt][ks] = cvt8(xp + ks*32 + g*8);
    }
    fx4 acc[4][2];
    for (int mt=0;mt<4;++mt) for (int nt=0;nt<2;++nt) acc[mt][nt] = (fx4){0.f,0.f,0.f,0.f};
    for (int mt=0;mt<4;++mt) for (int nt=0;nt<2;++nt) for (int ks=0;ks<2;++ks)
      acc[mt][nt] = MFMA16(aw[mt][ks], bx[nt][ks], acc[mt][nt]);
    unsigned short* O = Vt + (size_t)nh*64*2048;
    for (int mt=0;mt<4;++mt) for (int nt=0;nt<2;++nt) for (int rr=0;rr<4;++rr){
      int d = mt*16 + g*4 + rr, s = s0 + nt*16 + j;
      O[(size_t)d*2048 + s] = bfc(acc[mt][nt][rr]);
    }
  }
}

// ---------- kernel 2: flash attention, 32x32 QK + lane-local K=8 PV ----------
// grid: 1024 (XCD-swizzled): 64 nh x 16 qblocks of 128 rows. 4 waves x 32 q-cols.
// QK^T: z[kv][q] = mfma32x16(K, Q); lane (hi,c) holds kv = 4hi+(r&3)+8(r>>2), q=c.
// PV: per kv-window of 8, B[k=4hi+reg][q] == lane's own P quad -> mfma32x8, NO exchange.
// swizzle sw(row) = (row&7)^((row>>3)&3) applied at staging source + reads.
__global__ __launch_bounds__(256, 4) void flash_k(const unsigned short* __restrict__ Qb,
                                                  const unsigned short* __restrict__ Kb,
                                                  const unsigned short* __restrict__ Vt,
                                                  const unsigned long long* __restrict__ mT,
                                                  unsigned short* __restrict__ AO){
  __shared__ short lK[2][64*64];   // [buf][kv row][128B]
  __shared__ short lV[2][64*64];   // [buf][d  row][128B]
  int tid = threadIdx.x;
  int l = tid & 63, wv = tid >> 6, hi = l >> 5, c = l & 31;
  int swc = (c & 7) ^ ((c >> 3) & 3);   // sw(row) for rows c and c+32 (identical)
  int hi4 = hi*4;
  int bid0 = blockIdx.x;
  int bid = (bid0 & 7)*128 + (bid0 >> 3);   // XCD swizzle: each XCD gets 8 contiguous nh
  int nh = bid >> 4, qb = bid & 15;
  int n = nh >> 4, h = nh & 15;
  const unsigned short* Qp = Qb + (size_t)nh*131072;
  const unsigned short* Kp = Kb + (size_t)nh*131072;
  const unsigned short* Vp = Vt + (size_t)nh*131072;
  int q = qb*128 + wv*32 + c;
  bfx8 qf[4];
  #pragma unroll
  for (int s=0;s<4;++s) qf[s] = *(const bfx8*)(Qp + (size_t)q*64 + s*16 + hi*8);
  f32x16 accO0 = zero16(), accO1 = zero16();
  float ls = 0.f;
  const unsigned long long* mrow = mT + (size_t)n*65536 + q;
  int rowK0 = c*128;          // byte row offset (rows c)
  int rowK1 = rowK0 + 4096;   // rows c+32

  // staging: 4 waves cover 64x64 K and V tiles; 2 g2l16 each per lane per tile
  int sidx0 = wv*64 + l, sidx1 = sidx0 + 256;
  int srow0 = sidx0 >> 3, scs0 = (sidx0 & 7) ^ (srow0 & 7) ^ ((srow0 >> 3) & 3);
  int srow1 = sidx1 >> 3, scs1 = (sidx1 & 7) ^ (srow1 & 7) ^ ((srow1 >> 3) & 3);
  const unsigned short* Ksrc0 = Kp + (size_t)srow0*64 + scs0*8;
  const unsigned short* Ksrc1 = Kp + (size_t)srow1*64 + scs1*8;
  const unsigned short* Vsrc0 = Vp + (size_t)srow0*2048 + scs0*8;
  const unsigned short* Vsrc1 = Vp + (size_t)srow1*2048 + scs1*8;

  #define STAGE(b, kt) do { \
    g2l16(Ksrc0 + (size_t)(kt)*4096, (char*)lK[b] + sidx0*16); \
    g2l16(Ksrc1 + (size_t)(kt)*4096, (char*)lK[b] + sidx1*16); \
    g2l16(Vsrc0 + (size_t)(kt)*64,   (char*)lV[b] + sidx0*16); \
    g2l16(Vsrc1 + (size_t)(kt)*64,   (char*)lV[b] + sidx1*16); \
  } while(0)

  STAGE(0, 0);
  __syncthreads();
  unsigned long long mwcur = mrow[0];

  // PROC_TILE: tile T covers kv 32T..32T+31. Own Wt pairs = kv quads {32T+8w+4hi..+3}.
#define PROC_TILE(zz, mws, TT, VB) do { \
    unsigned Wt[8]; \
    _Pragma("unroll") \
    for (int wi=0; wi<8; ++wi){ \
      const int r0 = 2*wi; \
      const int pos = (r0&3) + 8*(r0>>2); \
      float p0_ = mexp((zz)[r0],   (mws), pos); \
      float p1_ = mexp((zz)[r0+1], (mws), pos+1); \
      ls += p0_ + p1_; \
      Wt[wi] = pack2(p0_, p1_); \
    } \
    _Pragma("unroll") \
    for (int wl=0; wl<4; ++wl){ \
      const int w = 4*(TT) + wl; \
      uint2 u2; u2.x = Wt[2*wl]; u2.y = Wt[2*wl+1]; \
      bfx4 pb = __builtin_bit_cast(bfx4, u2); \
      bfx4 vf0 = *(const bfx4*)((VB) + rowK0 + (((w ^ swc) << 4) + hi*8)); \
      bfx4 vf1 = *(const bfx4*)((VB) + rowK1 + (((w ^ swc) << 4) + hi*8)); \
      accO0 = mfma32x8(vf0, pb, accO0); \
      accO1 = mfma32x8(vf1, pb, accO1); \
    } \
  } while(0)

#define ATTN_ITER(BUF, NBUF, kt) do { \
    if ((kt) < 31) STAGE(NBUF, (kt)+1); \
    unsigned long long mw = mwcur; \
    mwcur = mrow[(size_t)((kt)+1 < 32 ? (kt)+1 : 31)*2048]; \
    const char* KB = (const char*)lK[BUF]; \
    const char* VB = (const char*)lV[BUF]; \
    f32x16 z0 = zero16(), z1 = zero16(); \
    _Pragma("unroll") \
    for (int s=0; s<4; ++s){ \
      bfx8 kf0 = *(const bfx8*)(KB + rowK0 + (((2*s+hi) ^ swc) << 4)); \
      bfx8 kf1 = *(const bfx8*)(KB + rowK1 + (((2*s+hi) ^ swc) << 4)); \
      z0 = MFMA32(kf0, qf[s], z0); \
      z1 = MFMA32(kf1, qf[s], z1); \
    } \
    unsigned mws0 = ((unsigned)mw) >> hi4; \
    unsigned mws1 = ((unsigned)(mw >> 32)) >> hi4; \
    PROC_TILE(z0, mws0, 0, VB); \
    PROC_TILE(z1, mws1, 1, VB); \
    __syncthreads(); \
  } while(0)

  #pragma unroll 1
  for (int kt2 = 0; kt2 < 32; kt2 += 2){
    ATTN_ITER(0, 1, kt2);
    ATTN_ITER(1, 0, kt2+1);
  }
#undef ATTN_ITER
#undef PROC_TILE
#undef STAGE

  ls += __shfl_xor(ls, 32);
  float inv = 1.0f / ls;
  unsigned short* aop = AO + ((size_t)n*2048 + q)*1024 + h*64;
  #pragma unroll
  for (int u=0; u<4; ++u){
    int d0 = u*8 + hi4;           // d-local = (r&3) + 8*(r>>2) + 4*hi, r=4u+rr
    ushort4 o;
    o.x = bfc(accO0[4*u+0]*inv); o.y = bfc(accO0[4*u+1]*inv);
    o.z = bfc(accO0[4*u+2]*inv); o.w = bfc(accO0[4*u+3]*inv);
    *(ushort4*)(aop + d0) = o;
    ushort4 o1;
    o1.x = bfc(accO1[4*u+0]*inv); o1.y = bfc(accO1[4*u+1]*inv);
    o1.z = bfc(accO1[4*u+2]*inv); o1.w = bfc(accO1[4*u+3]*inv);
    *(ushort4*)(aop + 32 + d0) = o1;
  }
}

// ---------- kernel 3: out = AO(8192x1024 bf16) @ Wo^T + bo (fp32), double-buffered ----------
__global__ __launch_bounds__(256) void gemm_k(const unsigned short* __restrict__ AO,
                                              const unsigned short* __restrict__ Wob,
                                              const float* __restrict__ bo, float* __restrict__ out){
  __shared__ short lA[2][128*32], lB[2][128*32];
  int tid = threadIdx.x, l = tid & 63, wv = tid >> 6, g = l >> 4, j = l & 15;
  int wr = wv >> 1, wc = wv & 1;
  int bid = blockIdx.x;
  int m0 = (bid >> 3)*128, n0 = (bid & 7)*128;
  fx4 acc[4][4];
  #pragma unroll
  for (int mt=0;mt<4;++mt) for (int nt=0;nt<4;++nt) acc[mt][nt] = (fx4){0.f,0.f,0.f,0.f};

  int sbase = wv*128;
  int sidx0 = sbase + l, sidx1 = sbase + 64 + l;
  int srow0 = sidx0 >> 2, sc0 = sidx0 & 3;
  int srow1 = sidx1 >> 2, sc1 = sidx1 & 3;
  const unsigned short* Asrc0 = AO  + (size_t)(m0+srow0)*1024 + sc0*8;
  const unsigned short* Asrc1 = AO  + (size_t)(m0+srow1)*1024 + sc1*8;
  const unsigned short* Bsrc0 = Wob + (size_t)(n0+srow0)*1024 + sc0*8;
  const unsigned short* Bsrc1 = Wob + (size_t)(n0+srow1)*1024 + sc1*8;

  #define GSTAGE(b, kb) do { \
    g2l16(Asrc0 + (kb)*32, (char*)lA[b] + sidx0*16); \
    g2l16(Asrc1 + (kb)*32, (char*)lA[b] + sidx1*16); \
    g2l16(Bsrc0 + (kb)*32, (char*)lB[b] + sidx0*16); \
    g2l16(Bsrc1 + (kb)*32, (char*)lB[b] + sidx1*16); \
  } while(0)

  GSTAGE(0, 0);
  __syncthreads();
  int b = 0;
  for (int kb = 0; kb < 32; ++kb){
    if (kb < 31) GSTAGE(b^1, kb+1);
    bfx8 af[4], bfr[4];
    #pragma unroll
    for (int mt=0;mt<4;++mt) af[mt]  = *(const bfx8*)((const char*)lA[b] + (wr*64 + mt*16 + j)*64 + g*16);
    #pragma unroll
    for (int nt=0;nt<4;++nt) bfr[nt] = *(const bfx8*)((const char*)lB[b] + (wc*64 + nt*16 + j)*64 + g*16);
    #pragma unroll
    for (int mt=0;mt<4;++mt)
      #pragma unroll
      for (int nt=0;nt<4;++nt)
        acc[mt][nt] = MFMA16(af[mt], bfr[nt], acc[mt][nt]);
    __syncthreads();
    b ^= 1;
  }
  #undef GSTAGE

  #pragma unroll
  for (int mt=0;mt<4;++mt)
    #pragma unroll
    for (int nt=0;nt<4;++nt){
      int mm = m0 + wr*64 + mt*16 + g*4;
      int oo = n0 + wc*64 + nt*16 + j;
      float bb = bo[oo];
      #pragma unroll
      for (int rr=0;rr<4;++rr)
        out[(size_t)(mm+rr)*1024 + oo] = acc[mt][nt][rr] + bb;
    }
}

// ---------- launch ----------
extern "C" void kernel_launch(void* const* d_in, const int* in_sizes, int n_in,
                              void* d_out, int out_size, void* d_ws, size_t ws_size,
                              hipStream_t stream){
  const float* V  = (const float*)d_in[0];
  const float* K  = (const float*)d_in[1];
  const float* Q  = (const float*)d_in[2];
  const int*   M  = (const int*)d_in[3];
  const float* Wv = (const float*)d_in[4];
  const float* Wk = (const float*)d_in[5];
  const float* Wq = (const float*)d_in[6];
  const float* Wo = (const float*)d_in[7];
  const float* bo = (const float*)d_in[8];

  char* ws = (char*)d_ws;
  unsigned short* Qb = (unsigned short*)(ws + ((size_t)0  << 20));  // 16MB
  unsigned short* Kb = (unsigned short*)(ws + ((size_t)16 << 20));  // 16MB
  unsigned short* Vt = (unsigned short*)(ws + ((size_t)32 << 20));  // 16MB
  unsigned short* AO = (unsigned short*)(ws + ((size_t)48 << 20));  // 16MB
  unsigned long long* mT = (unsigned long long*)(ws + ((size_t)64 << 20)); // 2MB
  unsigned short* Wob = (unsigned short*)(ws + ((size_t)66 << 20)); // 2MB

  hipLaunchKernelGGL(prep_k,  dim3(4608), dim3(256), 0, stream,
                     V, K, Q, Wv, Wk, Wq, M, Wo, Vt, Kb, Qb, mT, Wob);
  hipLaunchKernelGGL(flash_k, dim3(1024), dim3(256), 0, stream, Qb, Kb, Vt, mT, AO);
  hipLaunchKernelGGL(gemm_k,  dim3(512),  dim3(256), 0, stream, AO, Wob, bo, (float*)d_out);
}